// Round 1
// baseline (5518.616 us; speedup 1.0000x reference)
//
#include <hip/hip_runtime.h>
#include <hip/hip_bf16.h>

#define T_LEN 16384
#define HDIM 64
#define BATCH 64

// K = DELAY / OS_FACTOR = 1 / 1.5
#define KBLEND (1.0f / 1.5f)

__device__ __forceinline__ float tanh_fast(float x) {
    // tanh(x) = sign(x) * (1 - e) / (1 + e),  e = exp(-2|x|)
    float ax = fabsf(x);
    float e  = __expf(-2.0f * ax);
    float r  = __builtin_amdgcn_rcpf(1.0f + e);
    float t  = (1.0f - e) * r;
    return copysignf(t, x);
}

__global__ __launch_bounds__(HDIM, 1) void rnn_delayline_kernel(
    const float* __restrict__ x,      // [B, T, 1]
    const float* __restrict__ Wih,    // [H, 1]
    const float* __restrict__ Whh,    // [H, H] row-major; y[h] = sum_k Whh[h][k] * hprev[k]
    const float* __restrict__ bih,    // [H]
    const float* __restrict__ bhh,    // [H]
    float* __restrict__ out_states,   // [B, T, H]
    float* __restrict__ out_hlast)    // [B, H]
{
    const int lane = threadIdx.x;   // h index, 0..63 (one wave per block)
    const int b    = blockIdx.x;    // batch index

    __shared__ __align__(16) float hbuf[HDIM];
    __shared__ __align__(16) float xbuf[HDIM];

    // Load this lane's W_hh row into registers (contiguous per lane -> dwordx4)
    float w[HDIM];
    const float4* wrow = reinterpret_cast<const float4*>(Whh + lane * HDIM);
    #pragma unroll
    for (int kk = 0; kk < HDIM / 4; ++kk) {
        float4 v = wrow[kk];
        w[4*kk+0] = v.x; w[4*kk+1] = v.y; w[4*kk+2] = v.z; w[4*kk+3] = v.w;
    }
    const float wih  = Wih[lane];
    const float bias = bih[lane] + bhh[lane];   // b_ih + b_hh folded together

    float h = 0.0f;
    hbuf[lane] = 0.0f;

    const float* xb = x + (size_t)b * T_LEN;
    float xcur = xb[lane];          // chunk 0 of x (64 timesteps per chunk)
    xbuf[lane] = xcur;
    __syncthreads();                // once, before the sequential loop

    float* outp = out_states + ((size_t)b * T_LEN) * HDIM + lane;

    const int NCHUNK = T_LEN / HDIM;   // 256
    for (int c = 0; c < NCHUNK; ++c) {
        // Prefetch next x chunk early (lots of latency slack)
        float xnext = 0.0f;
        if (c + 1 < NCHUNK) xnext = xb[(size_t)(c + 1) * HDIM + lane];

        #pragma unroll 4
        for (int tt = 0; tt < HDIM; ++tt) {
            float xs = xbuf[tt];    // broadcast read (uniform addr, conflict-free)

            // y[lane] = sum_k Whh[lane][k] * h_prev[k]
            const float4* hb4 = reinterpret_cast<const float4*>(hbuf);
            float acc0 = 0.0f, acc1 = 0.0f, acc2 = 0.0f, acc3 = 0.0f;
            #pragma unroll
            for (int kk = 0; kk < HDIM / 4; ++kk) {
                float4 hv = hb4[kk];            // ds_read_b128 broadcast
                acc0 = fmaf(w[4*kk+0], hv.x, acc0);
                acc1 = fmaf(w[4*kk+1], hv.y, acc1);
                acc2 = fmaf(w[4*kk+2], hv.z, acc2);
                acc3 = fmaf(w[4*kk+3], hv.w, acc3);
            }
            float y = fmaf(xs, wih, bias) + ((acc0 + acc1) + (acc2 + acc3));

            float cell = tanh_fast(y);
            h = fmaf(KBLEND, cell - h, h);      // h = h + K*(cell - h)

            hbuf[lane] = h;                     // publish for next step
            // Single wave: LDS ops execute in order; fence stops compiler
            // from hoisting next iteration's reads above this write.
            asm volatile("" ::: "memory");

            *outp = h;                          // coalesced 256B/wave store
            outp += HDIM;
        }

        // Rotate x chunk into LDS (still single-wave ordered)
        asm volatile("" ::: "memory");
        xbuf[lane] = xnext;
        asm volatile("" ::: "memory");
    }

    out_hlast[b * HDIM + lane] = h;
}

extern "C" void kernel_launch(void* const* d_in, const int* in_sizes, int n_in,
                              void* d_out, int out_size, void* d_ws, size_t ws_size,
                              hipStream_t stream) {
    const float* x   = (const float*)d_in[0];
    const float* Wih = (const float*)d_in[1];
    const float* Whh = (const float*)d_in[2];
    const float* bih = (const float*)d_in[3];
    const float* bhh = (const float*)d_in[4];

    float* out_states = (float*)d_out;
    float* out_hlast  = out_states + (size_t)BATCH * T_LEN * HDIM;

    rnn_delayline_kernel<<<dim3(BATCH), dim3(HDIM), 0, stream>>>(
        x, Wih, Whh, bih, bhh, out_states, out_hlast);
}